// Round 5
// baseline (16.322 us; speedup 1.0000x reference)
//
#include <hip/hip_runtime.h>

#define NQ 4
#define DIMQ 16
#define NLAY 8
#define NOUT 4
#define NPAIR 136

// ---------------------------------------------------------------------------
// Setup kernel (1 block, 256 threads): builds M[3][10][10] in workspace.
//   out[b][m] = 0.5 + sum_{p,q} M_m[p][q] * G01[p] * G23[q]
//   f01[i] = ((i&2)?s0:c0)*((i&1)?s1:c1), f23 likewise for qubits 2,3
//   G01[p] = f01[i]*f01[k] over pairs i<=k (10 entries), G23 likewise.
// M folds A_m = sum_k w_k U_k^T D_m U_k + w4*D_m, symmetry-doubled, 0.5-scaled.
// ---------------------------------------------------------------------------
__global__ __launch_bounds__(256) void qnn_setup(const float* __restrict__ alpha,
                                                 const float* __restrict__ thetas,
                                                 float* __restrict__ M_out) {
    __shared__ float2 csT[128];
    __shared__ float2 csA[8];
    __shared__ float  U[NOUT][DIMQ][DIMQ];   // [k][col][row]
    __shared__ float  w[8];
    __shared__ float  Af[3][DIMQ][DIMQ];

    const int tid = threadIdx.x;

    // angle tables
    if (tid < 128) {
        const float t = thetas[tid] * 0.5f;
        csT[tid] = make_float2(cosf(t), sinf(t));
    } else if (tid < 135) {
        const float t = alpha[tid - 128] * 0.5f;
        csA[tid - 128] = make_float2(cosf(t), sinf(t));
    }
    __syncthreads();

    // simulate U_k columns (threads 0..63), ancilla weights (thread 64)
    if (tid < 64) {
        const int k = tid >> 4, col = tid & 15;
        float st[16];
        #pragma unroll
        for (int i = 0; i < 16; ++i) st[i] = (i == col) ? 1.0f : 0.0f;
        #pragma unroll 1
        for (int l = 0; l < NLAY; ++l) {
            #pragma unroll
            for (int q = 0; q < NQ; ++q) {
                const float2 cs = csT[k * 32 + l * 4 + q];
                const int pb = 1 << (3 - q);
                #pragma unroll
                for (int i0 = 0; i0 < 16; ++i0) {
                    if (i0 & pb) continue;
                    const int i1 = i0 | pb;
                    const float a0 = st[i0], a1 = st[i1];
                    st[i0] = cs.x * a0 - cs.y * a1;   // RY = [[c,-s],[s,c]]
                    st[i1] = cs.y * a0 + cs.x * a1;
                }
            }
            #pragma unroll
            for (int q = 0; q < NQ - 1; ++q) {  // CNOT(q,q+1) amplitude swaps
                const int cb = 1 << (3 - q), tb = 1 << (2 - q);
                #pragma unroll
                for (int i = 0; i < 16; ++i) {
                    if ((i & cb) && !(i & tb)) {
                        const int j = i | tb;
                        const float tmp = st[i]; st[i] = st[j]; st[j] = tmp;
                    }
                }
            }
        }
        #pragma unroll
        for (int r = 0; r < 16; ++r) U[k][col][r] = st[r];
    }
    if (tid == 64) {
        float e[8];
        #pragma unroll
        for (int i = 0; i < 8; ++i) e[i] = (i == 0) ? 1.0f : 0.0f;
        int idx = 0;
        #pragma unroll
        for (int l = 0; l < 3; ++l) {
            const int p = 2 - l, pb = 1 << p;
            #pragma unroll
            for (int i0 = 0; i0 < 8; ++i0) {
                if (i0 & pb) continue;
                const int i1 = i0 | pb;
                const float2 cs = csA[idx + (i0 >> (p + 1))];
                const float a0 = e[i0], a1 = e[i1];
                e[i0] = cs.x * a0 - cs.y * a1;
                e[i1] = cs.y * a0 + cs.x * a1;
            }
            idx += (1 << l);
        }
        for (int k = 0; k < 4; ++k) w[k] = e[k] * e[k];
        w[4] = e[4]*e[4] + e[5]*e[5] + e[6]*e[6] + e[7]*e[7];
    }
    __syncthreads();

    // full symmetric A_m (136 jobs)
    for (int j = tid; j < NPAIR; j += 256) {
        int r = j, t = 0;
        while (r >= 16 - t) { r -= 16 - t; ++t; }
        const int u = t + r;
        float gs[8] = {0,0,0,0,0,0,0,0};
        #pragma unroll
        for (int k = 0; k < NOUT; ++k) {
            #pragma unroll
            for (int rr = 0; rr < 16; ++rr)
                gs[rr >> 1] = fmaf(w[k], U[k][t][rr] * U[k][u][rr], gs[rr >> 1]);
        }
        float A0 = 0.f, A1 = 0.f, A2 = 0.f;
        #pragma unroll
        for (int c = 0; c < 8; ++c) {
            A0 += (c & 4) ? -gs[c] : gs[c];
            A1 += (c & 2) ? -gs[c] : gs[c];
            A2 += (c & 1) ? -gs[c] : gs[c];
        }
        if (t == u) {
            A0 += ((t >> 3) & 1) ? -w[4] : w[4];
            A1 += ((t >> 2) & 1) ? -w[4] : w[4];
            A2 += ((t >> 1) & 1) ? -w[4] : w[4];
        }
        Af[0][t][u] = A0; Af[0][u][t] = A0;
        Af[1][t][u] = A1; Af[1][u][t] = A1;
        Af[2][t][u] = A2; Af[2][u][t] = A2;
    }
    __syncthreads();

    // fold to M[3][10][10] in global ws; 0.5 output scale folded in
    for (int e = tid; e < 300; e += 256) {
        const int m = e / 100, r = e - m * 100, p = r / 10, q = r - p * 10;
        int i, k, jj, ll;
        if (p < 4)      { i = 0; k = p; }
        else if (p < 7) { i = 1; k = p - 3; }
        else if (p < 9) { i = 2; k = p - 5; }
        else            { i = 3; k = 3; }
        if (q < 4)      { jj = 0; ll = q; }
        else if (q < 7) { jj = 1; ll = q - 3; }
        else if (q < 9) { jj = 2; ll = q - 5; }
        else            { jj = 3; ll = 3; }
        float v;
        if (i < k && jj < ll)       v = Af[m][4*i+jj][4*k+ll] + Af[m][4*i+ll][4*k+jj];
        else if (i == k && jj < ll) v = Af[m][4*i+jj][4*i+ll];
        else if (i < k && jj == ll) v = Af[m][4*i+jj][4*k+jj];
        else                        v = 0.5f * Af[m][4*i+jj][4*i+jj];
        M_out[e] = v;
    }
}

// ---------------------------------------------------------------------------
// Main kernel: 1 sample/thread, no LDS, no barriers. M read with wave-uniform
// compile-time offsets -> scalarized s_load (SMEM pipe), overlaps VALU.
// ---------------------------------------------------------------------------
__global__ __launch_bounds__(256) void qnn_main(const float4* __restrict__ x,
                                                const float* __restrict__ M,
                                                float* __restrict__ out,
                                                int batch) {
    const int b = blockIdx.x * 256 + threadIdx.x;
    if (b >= batch) return;

    const float4 xv = x[b];
    float c0, s0, c1, s1, c2, s2, c3, s3;
    sincospif(xv.x, &s0, &c0);
    sincospif(xv.y, &s1, &c1);
    sincospif(xv.z, &s2, &c2);
    sincospif(xv.w, &s3, &c3);

    float f01[4], f23[4];
    f01[0] = c0 * c1; f01[1] = c0 * s1; f01[2] = s0 * c1; f01[3] = s0 * s1;
    f23[0] = c2 * c3; f23[1] = c2 * s3; f23[2] = s2 * c3; f23[3] = s2 * s3;

    float G01[10], G23[10];
    {
        int idx = 0;
        #pragma unroll
        for (int i = 0; i < 4; ++i)
            #pragma unroll
            for (int k = i; k < 4; ++k) { G01[idx] = f01[i] * f01[k]; ++idx; }
        idx = 0;
        #pragma unroll
        for (int j = 0; j < 4; ++j)
            #pragma unroll
            for (int l = j; l < 4; ++l) { G23[idx] = f23[j] * f23[l]; ++idx; }
    }

    float acc0 = 0.5f, acc1 = 0.5f, acc2 = 0.5f;
    #pragma unroll
    for (int p = 0; p < 10; ++p) {
        float z0 = M[        p * 10] * G23[0];
        float z1 = M[100 +   p * 10] * G23[0];
        float z2 = M[200 +   p * 10] * G23[0];
        #pragma unroll
        for (int q = 1; q < 10; ++q) {
            z0 = fmaf(M[        p * 10 + q], G23[q], z0);
            z1 = fmaf(M[100 +   p * 10 + q], G23[q], z1);
            z2 = fmaf(M[200 +   p * 10 + q], G23[q], z2);
        }
        acc0 = fmaf(G01[p], z0, acc0);
        acc1 = fmaf(G01[p], z1, acc1);
        acc2 = fmaf(G01[p], z2, acc2);
    }

    out[b * 3 + 0] = acc0;
    out[b * 3 + 1] = acc1;
    out[b * 3 + 2] = acc2;
}

extern "C" void kernel_launch(void* const* d_in, const int* in_sizes, int n_in,
                              void* d_out, int out_size, void* d_ws, size_t ws_size,
                              hipStream_t stream) {
    const float* x      = (const float*)d_in[0];   // (131072, 4) f32
    const float* alpha  = (const float*)d_in[1];   // (7,) f32
    const float* thetas = (const float*)d_in[2];   // (4, 32) f32
    float* M = (float*)d_ws;                       // 300 floats scratch

    qnn_setup<<<1, 256, 0, stream>>>(alpha, thetas, M);

    const int batch = in_sizes[0] / 4;                 // 131072
    const int blocks = (batch + 255) / 256;            // 512
    qnn_main<<<blocks, 256, 0, stream>>>((const float4*)x, M, (float*)d_out, batch);
}